// Round 2
// baseline (857.533 us; speedup 1.0000x reference)
//
#include <hip/hip_runtime.h>
#include <hip/hip_bf16.h>

// Problem constants
#define B_   4
#define CIN  32
#define HIN  192
#define WIN  192
#define HO   96
#define WO   96
#define L_   9216      // HO*WO
#define C_   64        // DIM
#define DI   128       // d_inner
#define DS   16        // d_state
#define NC   128       // scan chunks
#define CL   72        // chunk length = L_/NC

// ---------------------------------------------------------------------------
// K1: ReflectionPad(1) + Conv2d(32->64, k4, s2) + bias, then LayerNorm over C.
// Writes seq (pre-LN, == xc in seq layout) and nrm. 16 pixels per block.
// ---------------------------------------------------------------------------
__global__ __launch_bounds__(256) void k1_conv_ln(
    const float* __restrict__ x, const float* __restrict__ cw, const float* __restrict__ cb,
    const float* __restrict__ g, const float* __restrict__ be,
    float* __restrict__ seq, float* __restrict__ nrm)
{
    __shared__ float patch[16 * 512];   // 32 KB
    const int pb = blockIdx.x * 16;     // global pixel base in [0, B*L)
    const int b = pb / L_;
    const int lbase = pb % L_;          // 16 | L_ so a block never straddles b

    for (int i = threadIdx.x; i < 16 * 512; i += 256) {
        int px = i >> 9;
        int kk = i & 511;               // ci*16 + kh*4 + kw
        int ci = kk >> 4, kh = (kk >> 2) & 3, kw = kk & 3;
        int l = lbase + px;
        int oh = l / WO, ow = l - oh * WO;
        int ih = 2 * oh + kh - 1; ih = ih < 0 ? -ih : (ih >= HIN ? 2 * HIN - 2 - ih : ih);
        int iw = 2 * ow + kw - 1; iw = iw < 0 ? -iw : (iw >= WIN ? 2 * WIN - 2 - iw : iw);
        patch[i] = x[((b * CIN + ci) * HIN + ih) * WIN + iw];
    }
    __syncthreads();

    const int c = threadIdx.x & 63;
    const int pp = threadIdx.x >> 6;    // wave id: 4 pixels per wave
    float bias = cb[c];
    float acc[4] = {bias, bias, bias, bias};
    const float* p0 = &patch[(pp * 4 + 0) * 512];
    const float* p1 = &patch[(pp * 4 + 1) * 512];
    const float* p2 = &patch[(pp * 4 + 2) * 512];
    const float* p3 = &patch[(pp * 4 + 3) * 512];
    const float* wrow = cw + c * 512;

    for (int k = 0; k < 512; k += 4) {
        float4 w4 = *reinterpret_cast<const float4*>(wrow + k);
        float4 q0 = *reinterpret_cast<const float4*>(p0 + k);
        float4 q1 = *reinterpret_cast<const float4*>(p1 + k);
        float4 q2 = *reinterpret_cast<const float4*>(p2 + k);
        float4 q3 = *reinterpret_cast<const float4*>(p3 + k);
        acc[0] += w4.x * q0.x + w4.y * q0.y + w4.z * q0.z + w4.w * q0.w;
        acc[1] += w4.x * q1.x + w4.y * q1.y + w4.z * q1.z + w4.w * q1.w;
        acc[2] += w4.x * q2.x + w4.y * q2.y + w4.z * q2.z + w4.w * q2.w;
        acc[3] += w4.x * q3.x + w4.y * q3.y + w4.z * q3.z + w4.w * q3.w;
    }

    float gc = g[c], bc = be[c];
    #pragma unroll
    for (int j = 0; j < 4; ++j) {
        float v = acc[j];
        float s1 = v, s2 = v * v;
        #pragma unroll
        for (int off = 32; off >= 1; off >>= 1) {
            s1 += __shfl_xor(s1, off);
            s2 += __shfl_xor(s2, off);
        }
        float mu = s1 * (1.0f / 64.0f);
        float var = s2 * (1.0f / 64.0f) - mu * mu;
        float r = rsqrtf(var + 1e-5f);
        int row = b * L_ + lbase + pp * 4 + j;
        seq[row * 64 + c] = v;
        nrm[row * 64 + c] = (v - mu) * r * gc + bc;
    }
}

// ---------------------------------------------------------------------------
// K2: in_proj. xz = nrm @ W.T (W: 256x64). xm = xz[:, :128], sz = silu(xz[:,128:]).
// One row per block, 256 threads = 256 output features.
// ---------------------------------------------------------------------------
__global__ __launch_bounds__(256) void k2_inproj(
    const float* __restrict__ nrm, const float* __restrict__ w,
    float* __restrict__ xm, float* __restrict__ sz)
{
    __shared__ float rowv[64];
    const int row = blockIdx.x;
    if (threadIdx.x < 64) rowv[threadIdx.x] = nrm[row * 64 + threadIdx.x];
    __syncthreads();
    const int n = threadIdx.x;
    const float* wr = w + n * 64;
    float acc = 0.f;
    #pragma unroll
    for (int k = 0; k < 64; k += 4) {
        float4 w4 = *reinterpret_cast<const float4*>(wr + k);
        acc += w4.x * rowv[k] + w4.y * rowv[k + 1]
             + w4.z * rowv[k + 2] + w4.w * rowv[k + 3];
    }
    if (n < DI) xm[row * DI + n] = acc;
    else        sz[row * DI + (n - DI)] = acc / (1.0f + __expf(-acc));
}

// ---------------------------------------------------------------------------
// K3: causal depthwise conv1d (k=4) + bias + SiLU along L (per batch).
// ---------------------------------------------------------------------------
__global__ __launch_bounds__(256) void k3_dwconv(
    const float* __restrict__ xm, const float* __restrict__ w,
    const float* __restrict__ bia, float* __restrict__ u)
{
    const int idx = blockIdx.x * 256 + threadIdx.x;   // over B*L*DI
    const int c = idx & (DI - 1);
    const int bl = idx >> 7;        // b*L + l
    const int l = bl % L_;
    float w0 = w[c * 4 + 0], w1 = w[c * 4 + 1];
    float w2 = w[c * 4 + 2], w3 = w[c * 4 + 3];
    float acc = bia[c];
    if (l >= 3) acc += xm[(bl - 3) * DI + c] * w0;
    if (l >= 2) acc += xm[(bl - 2) * DI + c] * w1;
    if (l >= 1) acc += xm[(bl - 1) * DI + c] * w2;
    acc += xm[bl * DI + c] * w3;
    u[idx] = acc / (1.0f + __expf(-acc));
}

// ---------------------------------------------------------------------------
// K4: x_dbl = u @ x_proj_w.T (36x128); dt = softplus(x_dbl[:, :4] @ dt_proj_w.T + b).
// One row per block, 128 threads.
// ---------------------------------------------------------------------------
__global__ __launch_bounds__(128) void k4_xproj_dt(
    const float* __restrict__ u, const float* __restrict__ xpw,
    const float* __restrict__ dtw, const float* __restrict__ dtb,
    float* __restrict__ Bs, float* __restrict__ Cs, float* __restrict__ dt)
{
    __shared__ float ur[128];
    __shared__ float xd[4];
    const int row = blockIdx.x;
    const int t = threadIdx.x;
    ur[t] = u[row * DI + t];
    __syncthreads();
    if (t < 36) {
        const float* wr = xpw + t * 128;
        float acc = 0.f;
        #pragma unroll
        for (int k = 0; k < 128; k += 4) {
            float4 w4 = *reinterpret_cast<const float4*>(wr + k);
            acc += w4.x * ur[k] + w4.y * ur[k + 1]
                 + w4.z * ur[k + 2] + w4.w * ur[k + 3];
        }
        if (t < 4)       xd[t] = acc;
        else if (t < 20) Bs[row * DS + (t - 4)] = acc;
        else             Cs[row * DS + (t - 20)] = acc;
    }
    __syncthreads();
    float dv = dtb[t];
    #pragma unroll
    for (int r = 0; r < 4; ++r) dv += xd[r] * dtw[t * 4 + r];
    dt[row * DI + t] = dv > 20.f ? dv : log1pf(__expf(dv));
}

// ---------------------------------------------------------------------------
// K5a: scan pass A — per (b, chunk, channel) compute P = prod(dA), hp = h with h_in=0.
// ---------------------------------------------------------------------------
__global__ __launch_bounds__(128) void k5a(
    const float* __restrict__ dt, const float* __restrict__ u,
    const float* __restrict__ Bsb, const float* __restrict__ alog,
    float* __restrict__ P, float* __restrict__ HP)
{
    const int bk = blockIdx.x;          // b*NC + k
    const int b = bk / NC, k = bk - b * NC;
    const int c = threadIdx.x;
    float As[DS];
    #pragma unroll
    for (int s = 0; s < DS; ++s) As[s] = -__expf(alog[c * DS + s]);
    float Pp[DS], hp[DS];
    #pragma unroll
    for (int s = 0; s < DS; ++s) { Pp[s] = 1.f; hp[s] = 0.f; }

    const int l0 = k * CL;
    for (int i = 0; i < CL; ++i) {
        const int row = b * L_ + l0 + i;
        float dtv = dt[row * DI + c];
        float uv = u[row * DI + c];
        float dtu = dtv * uv;
        const float4* Bq = reinterpret_cast<const float4*>(Bsb + row * DS);
        float Bv[DS];
        *reinterpret_cast<float4*>(&Bv[0])  = Bq[0];
        *reinterpret_cast<float4*>(&Bv[4])  = Bq[1];
        *reinterpret_cast<float4*>(&Bv[8])  = Bq[2];
        *reinterpret_cast<float4*>(&Bv[12]) = Bq[3];
        #pragma unroll
        for (int s = 0; s < DS; ++s) {
            float dA = __expf(dtv * As[s]);
            hp[s] = dA * hp[s] + dtu * Bv[s];
            Pp[s] *= dA;
        }
    }
    float* Pd = P + bk * 2048 + c * DS;
    float* Hd = HP + bk * 2048 + c * DS;
    #pragma unroll
    for (int q = 0; q < 4; ++q) {
        reinterpret_cast<float4*>(Pd)[q] = *reinterpret_cast<float4*>(&Pp[q * 4]);
        reinterpret_cast<float4*>(Hd)[q] = *reinterpret_cast<float4*>(&hp[q * 4]);
    }
}

// ---------------------------------------------------------------------------
// K5b: scan pass B — serial scan over the NC chunk carries per (b, c, s).
// ---------------------------------------------------------------------------
__global__ __launch_bounds__(256) void k5b(
    const float* __restrict__ P, const float* __restrict__ HP, float* __restrict__ HI)
{
    const int t = blockIdx.x * 256 + threadIdx.x;   // 0..8191
    const int b = t >> 11, cs = t & 2047;
    float carry = 0.f;
    for (int k = 0; k < NC; ++k) {
        const int idx = (b * NC + k) * 2048 + cs;
        HI[idx] = carry;
        carry = HP[idx] + P[idx] * carry;
    }
}

// ---------------------------------------------------------------------------
// K5c: scan pass C — replay with h_in, compute y, fuse (y + u*D) * silu(z).
// ---------------------------------------------------------------------------
__global__ __launch_bounds__(128) void k5c(
    const float* __restrict__ dt, const float* __restrict__ u,
    const float* __restrict__ Bsb, const float* __restrict__ Csb,
    const float* __restrict__ sz, const float* __restrict__ alog,
    const float* __restrict__ Db, const float* __restrict__ HI,
    float* __restrict__ yc)
{
    const int bk = blockIdx.x;
    const int b = bk / NC, k = bk - b * NC;
    const int c = threadIdx.x;
    float As[DS];
    #pragma unroll
    for (int s = 0; s < DS; ++s) As[s] = -__expf(alog[c * DS + s]);
    const float Dc = Db[c];
    float h[DS];
    const float* Hs = HI + bk * 2048 + c * DS;
    #pragma unroll
    for (int q = 0; q < 4; ++q)
        *reinterpret_cast<float4*>(&h[q * 4]) = reinterpret_cast<const float4*>(Hs)[q];

    const int l0 = k * CL;
    for (int i = 0; i < CL; ++i) {
        const int row = b * L_ + l0 + i;
        float dtv = dt[row * DI + c];
        float uv = u[row * DI + c];
        float szv = sz[row * DI + c];
        float dtu = dtv * uv;
        const float4* Bq = reinterpret_cast<const float4*>(Bsb + row * DS);
        const float4* Cq = reinterpret_cast<const float4*>(Csb + row * DS);
        float Bv[DS], Cv[DS];
        #pragma unroll
        for (int q = 0; q < 4; ++q) {
            *reinterpret_cast<float4*>(&Bv[q * 4]) = Bq[q];
            *reinterpret_cast<float4*>(&Cv[q * 4]) = Cq[q];
        }
        float ya[4] = {0.f, 0.f, 0.f, 0.f};
        #pragma unroll
        for (int s = 0; s < DS; ++s) {
            float dA = __expf(dtv * As[s]);
            h[s] = dA * h[s] + dtu * Bv[s];
            ya[s & 3] += h[s] * Cv[s];
        }
        float yv = (ya[0] + ya[1]) + (ya[2] + ya[3]);
        yc[row * DI + c] = (yv + uv * Dc) * szv;
    }
}

// ---------------------------------------------------------------------------
// K6: out_proj (64x128) + residual (+2*seq) + transpose store to NCHW fp32.
// ---------------------------------------------------------------------------
__global__ __launch_bounds__(64) void k6_outproj(
    const float* __restrict__ yc, const float* __restrict__ opw,
    const float* __restrict__ seq, float* __restrict__ out)
{
    __shared__ float yr[128];
    const int row = blockIdx.x;
    yr[threadIdx.x] = yc[row * DI + threadIdx.x];
    yr[threadIdx.x + 64] = yc[row * DI + 64 + threadIdx.x];
    __syncthreads();
    const int c = threadIdx.x;
    const float* wr = opw + c * 128;
    float acc = 0.f;
    #pragma unroll
    for (int k = 0; k < 128; k += 4) {
        float4 w4 = *reinterpret_cast<const float4*>(wr + k);
        acc += w4.x * yr[k] + w4.y * yr[k + 1]
             + w4.z * yr[k + 2] + w4.w * yr[k + 3];
    }
    float res = acc + 2.0f * seq[row * 64 + c];
    const int b = row / L_, l = row - b * L_;
    out[(b * 64 + c) * L_ + l] = res;
}

extern "C" void kernel_launch(void* const* d_in, const int* in_sizes, int n_in,
                              void* d_out, int out_size, void* d_ws, size_t ws_size,
                              hipStream_t stream)
{
    const float* x    = (const float*)d_in[0];
    const float* cw   = (const float*)d_in[1];
    const float* cb   = (const float*)d_in[2];
    const float* g    = (const float*)d_in[3];
    const float* be   = (const float*)d_in[4];
    const float* ipw  = (const float*)d_in[5];
    const float* c1w  = (const float*)d_in[6];
    const float* c1b  = (const float*)d_in[7];
    const float* xpw  = (const float*)d_in[8];
    const float* dtw  = (const float*)d_in[9];
    const float* dtb  = (const float*)d_in[10];
    const float* alog = (const float*)d_in[11];
    const float* Db   = (const float*)d_in[12];
    const float* opw  = (const float*)d_in[13];

    float* ws  = (float*)d_ws;
    float* seq = ws;                      // 2,359,296
    float* nrm = seq + 2359296;           // 2,359,296
    float* xm  = nrm + 2359296;           // 4,718,592
    float* sz  = xm + 4718592;            // 4,718,592
    float* u   = sz + 4718592;            // 4,718,592
    float* dt  = u + 4718592;             // 4,718,592
    float* Bs  = dt + 4718592;            // 589,824
    float* Cs  = Bs + 589824;             // 589,824
    float* P   = Cs + 589824;             // 1,048,576
    float* HP  = P + 1048576;             // 1,048,576
    float* HI  = HP + 1048576;            // 1,048,576
    float* yc  = xm;                      // reuse xm (dead after k3)

    k1_conv_ln<<<2304, 256, 0, stream>>>(x, cw, cb, g, be, seq, nrm);
    k2_inproj<<<36864, 256, 0, stream>>>(nrm, ipw, xm, sz);
    k3_dwconv<<<18432, 256, 0, stream>>>(xm, c1w, c1b, u);
    k4_xproj_dt<<<36864, 128, 0, stream>>>(u, xpw, dtw, dtb, Bs, Cs, dt);
    k5a<<<B_ * NC, 128, 0, stream>>>(dt, u, Bs, alog, P, HP);
    k5b<<<32, 256, 0, stream>>>(P, HP, HI);
    k5c<<<B_ * NC, 128, 0, stream>>>(dt, u, Bs, Cs, sz, alog, Db, HI, yc);
    k6_outproj<<<36864, 64, 0, stream>>>(yc, opw, seq, (float*)d_out);
}

// Round 3
// 447.584 us; speedup vs baseline: 1.9159x; 1.9159x over previous
//
#include <hip/hip_runtime.h>
#include <hip/hip_bf16.h>

// Problem constants
#define B_   4
#define CIN  32
#define HIN  192
#define WIN  192
#define HO   96
#define WO   96
#define L_   9216      // HO*WO
#define C_   64        // DIM
#define DI   128       // d_inner
#define DS   16        // d_state
#define NC   256       // scan chunks
#define CL   36        // chunk length = L_*B_/ (NC*B_) = L_/NC

// ---------------------------------------------------------------------------
// K0: prep — transpose weights into [k][n] layouts; fuse dt_proj@x_proj[:4].
//   W2t[64][256]  : W2t[k][n] = in_proj_w[n][k]
//   Wct[128][160] : n<128 -> sum_r dtw[n][r]*xpw[r][k]; n<144 -> xpw[4+n-128][k];
//                   else xpw[20+n-144][k]
//   W6t[128][64]  : W6t[k][n] = out_proj_w[n][k]
// ---------------------------------------------------------------------------
__global__ __launch_bounds__(256) void k0_prep(
    const float* __restrict__ ipw, const float* __restrict__ xpw,
    const float* __restrict__ dtw, const float* __restrict__ opw,
    float* __restrict__ W2t, float* __restrict__ Wct, float* __restrict__ W6t)
{
    int i = blockIdx.x * 256 + threadIdx.x;
    if (i < 16384) {
        int k = i >> 8, n = i & 255;
        W2t[i] = ipw[n * 64 + k];
    } else if (i < 16384 + 20480) {
        int j = i - 16384;
        int k = j / 160, n = j - k * 160;
        float v;
        if (n < 128) {
            v = dtw[n * 4 + 0] * xpw[0 * 128 + k] + dtw[n * 4 + 1] * xpw[1 * 128 + k]
              + dtw[n * 4 + 2] * xpw[2 * 128 + k] + dtw[n * 4 + 3] * xpw[3 * 128 + k];
        } else if (n < 144) {
            v = xpw[(4 + n - 128) * 128 + k];
        } else {
            v = xpw[(20 + n - 144) * 128 + k];
        }
        Wct[j] = v;
    } else if (i < 16384 + 20480 + 8192) {
        int j = i - 16384 - 20480;
        int k = j >> 6, n = j & 63;
        W6t[j] = opw[n * 128 + k];
    }
}

// ---------------------------------------------------------------------------
// K1: ReflectionPad(1) + Conv2d(32->64, k4, s2) + bias, then LayerNorm over C.
// ---------------------------------------------------------------------------
__global__ __launch_bounds__(256) void k1_conv_ln(
    const float* __restrict__ x, const float* __restrict__ cw, const float* __restrict__ cb,
    const float* __restrict__ g, const float* __restrict__ be,
    float* __restrict__ seq, float* __restrict__ nrm)
{
    __shared__ float patch[16 * 512];   // 32 KB
    const int pb = blockIdx.x * 16;
    const int b = pb / L_;
    const int lbase = pb % L_;

    for (int i = threadIdx.x; i < 16 * 512; i += 256) {
        int px = i >> 9;
        int kk = i & 511;
        int ci = kk >> 4, kh = (kk >> 2) & 3, kw = kk & 3;
        int l = lbase + px;
        int oh = l / WO, ow = l - oh * WO;
        int ih = 2 * oh + kh - 1; ih = ih < 0 ? -ih : (ih >= HIN ? 2 * HIN - 2 - ih : ih);
        int iw = 2 * ow + kw - 1; iw = iw < 0 ? -iw : (iw >= WIN ? 2 * WIN - 2 - iw : iw);
        patch[i] = x[((b * CIN + ci) * HIN + ih) * WIN + iw];
    }
    __syncthreads();

    const int c = threadIdx.x & 63;
    const int pp = threadIdx.x >> 6;
    float bias = cb[c];
    float acc[4] = {bias, bias, bias, bias};
    const float* p0 = &patch[(pp * 4 + 0) * 512];
    const float* p1 = &patch[(pp * 4 + 1) * 512];
    const float* p2 = &patch[(pp * 4 + 2) * 512];
    const float* p3 = &patch[(pp * 4 + 3) * 512];
    const float* wrow = cw + c * 512;

    for (int k = 0; k < 512; k += 4) {
        float4 w4 = *reinterpret_cast<const float4*>(wrow + k);
        float4 q0 = *reinterpret_cast<const float4*>(p0 + k);
        float4 q1 = *reinterpret_cast<const float4*>(p1 + k);
        float4 q2 = *reinterpret_cast<const float4*>(p2 + k);
        float4 q3 = *reinterpret_cast<const float4*>(p3 + k);
        acc[0] += w4.x * q0.x + w4.y * q0.y + w4.z * q0.z + w4.w * q0.w;
        acc[1] += w4.x * q1.x + w4.y * q1.y + w4.z * q1.z + w4.w * q1.w;
        acc[2] += w4.x * q2.x + w4.y * q2.y + w4.z * q2.z + w4.w * q2.w;
        acc[3] += w4.x * q3.x + w4.y * q3.y + w4.z * q3.z + w4.w * q3.w;
    }

    float gc = g[c], bc = be[c];
    #pragma unroll
    for (int j = 0; j < 4; ++j) {
        float v = acc[j];
        float s1 = v, s2 = v * v;
        #pragma unroll
        for (int off = 32; off >= 1; off >>= 1) {
            s1 += __shfl_xor(s1, off);
            s2 += __shfl_xor(s2, off);
        }
        float mu = s1 * (1.0f / 64.0f);
        float var = s2 * (1.0f / 64.0f) - mu * mu;
        float r = rsqrtf(var + 1e-5f);
        int row = b * L_ + lbase + pp * 4 + j;
        seq[row * 64 + c] = v;
        nrm[row * 64 + c] = (v - mu) * r * gc + bc;
    }
}

// ---------------------------------------------------------------------------
// G2: in_proj GEMM. 64 rows/block, N=256, K=64. W2t streamed from L2.
// thread: n4=(t&63)*4, r16=(t>>6)*16 -> acc[16][4].
// ---------------------------------------------------------------------------
__global__ __launch_bounds__(256) void g2_inproj(
    const float* __restrict__ nrm, const float* __restrict__ W2t,
    float* __restrict__ xm, float* __restrict__ sz)
{
    __shared__ float xL[64][68];
    const int row0 = blockIdx.x * 64;
    const int t = threadIdx.x;

    for (int idx = t; idx < 1024; idx += 256) {
        int r = idx >> 4, kq = (idx & 15) * 4;
        float4 v = *reinterpret_cast<const float4*>(nrm + (row0 + r) * 64 + kq);
        *reinterpret_cast<float4*>(&xL[r][kq]) = v;
    }
    __syncthreads();

    const int n4 = (t & 63) * 4;
    const int r16 = (t >> 6) * 16;
    float acc[16][4];
    #pragma unroll
    for (int j = 0; j < 16; ++j)
        acc[j][0] = acc[j][1] = acc[j][2] = acc[j][3] = 0.f;

    for (int k = 0; k < 64; ++k) {
        float4 w = *reinterpret_cast<const float4*>(W2t + k * 256 + n4);
        #pragma unroll
        for (int j = 0; j < 16; ++j) {
            float xv = xL[r16 + j][k];
            acc[j][0] += xv * w.x; acc[j][1] += xv * w.y;
            acc[j][2] += xv * w.z; acc[j][3] += xv * w.w;
        }
    }

    #pragma unroll
    for (int j = 0; j < 16; ++j) {
        int row = row0 + r16 + j;
        float4 v = {acc[j][0], acc[j][1], acc[j][2], acc[j][3]};
        if (n4 < 128) {
            *reinterpret_cast<float4*>(xm + row * DI + n4) = v;
        } else {
            v.x = v.x / (1.f + __expf(-v.x));
            v.y = v.y / (1.f + __expf(-v.y));
            v.z = v.z / (1.f + __expf(-v.z));
            v.w = v.w / (1.f + __expf(-v.w));
            *reinterpret_cast<float4*>(sz + row * DI + (n4 - 128)) = v;
        }
    }
}

// ---------------------------------------------------------------------------
// K3: causal depthwise conv1d (k=4) + bias + SiLU. 4 outputs per thread.
// ---------------------------------------------------------------------------
__global__ __launch_bounds__(256) void k3_dwconv(
    const float* __restrict__ xm, const float* __restrict__ w,
    const float* __restrict__ bia, float* __restrict__ u)
{
    const int gid = blockIdx.x * 256 + threadIdx.x;   // over B*L/4 * 128
    const int c = gid & 127;
    const int g = gid >> 7;          // 4-row group
    const int bl0 = g * 4;
    const int l0 = bl0 % L_;         // wave-uniform

    float w0 = w[c * 4 + 0], w1 = w[c * 4 + 1];
    float w2 = w[c * 4 + 2], w3 = w[c * 4 + 3];
    float bv = bia[c];

    float xv[7];
    if (l0 == 0) { xv[0] = xv[1] = xv[2] = 0.f; }
    else {
        xv[0] = xm[(bl0 - 3) * DI + c];
        xv[1] = xm[(bl0 - 2) * DI + c];
        xv[2] = xm[(bl0 - 1) * DI + c];
    }
    #pragma unroll
    for (int j = 0; j < 4; ++j) xv[3 + j] = xm[(bl0 + j) * DI + c];

    #pragma unroll
    for (int j = 0; j < 4; ++j) {
        float a = bv + xv[j] * w0 + xv[j + 1] * w1 + xv[j + 2] * w2 + xv[j + 3] * w3;
        u[(bl0 + j) * DI + c] = a / (1.f + __expf(-a));
    }
}

// ---------------------------------------------------------------------------
// G4: fused x_proj + dt_proj GEMM. 64 rows/block, N=160 (dt128|B16|C16), K=128.
// 320 threads: n4=(t%40)*4, r8=(t/40)*8 -> acc[8][4].
// ---------------------------------------------------------------------------
__global__ __launch_bounds__(320) void g4_xproj(
    const float* __restrict__ u, const float* __restrict__ Wct,
    const float* __restrict__ dtb,
    float* __restrict__ dt, float* __restrict__ Bs, float* __restrict__ Cs)
{
    __shared__ float xL[64][132];
    const int row0 = blockIdx.x * 64;
    const int t = threadIdx.x;

    for (int idx = t; idx < 2048; idx += 320) {
        int r = idx >> 5, kq = (idx & 31) * 4;
        float4 v = *reinterpret_cast<const float4*>(u + (row0 + r) * DI + kq);
        *reinterpret_cast<float4*>(&xL[r][kq]) = v;
    }
    __syncthreads();

    const int nt = t % 40;
    const int n4 = nt * 4;
    const int r8 = (t / 40) * 8;
    float acc[8][4];
    #pragma unroll
    for (int j = 0; j < 8; ++j)
        acc[j][0] = acc[j][1] = acc[j][2] = acc[j][3] = 0.f;

    for (int k = 0; k < 128; ++k) {
        float4 w = *reinterpret_cast<const float4*>(Wct + k * 160 + n4);
        #pragma unroll
        for (int j = 0; j < 8; ++j) {
            float xv = xL[r8 + j][k];
            acc[j][0] += xv * w.x; acc[j][1] += xv * w.y;
            acc[j][2] += xv * w.z; acc[j][3] += xv * w.w;
        }
    }

    if (n4 < 128) {
        float4 db = *reinterpret_cast<const float4*>(dtb + n4);
        #pragma unroll
        for (int j = 0; j < 8; ++j) {
            int row = row0 + r8 + j;
            float4 v = {acc[j][0] + db.x, acc[j][1] + db.y,
                        acc[j][2] + db.z, acc[j][3] + db.w};
            v.x = v.x > 20.f ? v.x : log1pf(__expf(v.x));
            v.y = v.y > 20.f ? v.y : log1pf(__expf(v.y));
            v.z = v.z > 20.f ? v.z : log1pf(__expf(v.z));
            v.w = v.w > 20.f ? v.w : log1pf(__expf(v.w));
            *reinterpret_cast<float4*>(dt + row * DI + n4) = v;
        }
    } else if (n4 < 144) {
        #pragma unroll
        for (int j = 0; j < 8; ++j) {
            int row = row0 + r8 + j;
            float4 v = {acc[j][0], acc[j][1], acc[j][2], acc[j][3]};
            *reinterpret_cast<float4*>(Bs + row * DS + (n4 - 128)) = v;
        }
    } else {
        #pragma unroll
        for (int j = 0; j < 8; ++j) {
            int row = row0 + r8 + j;
            float4 v = {acc[j][0], acc[j][1], acc[j][2], acc[j][3]};
            *reinterpret_cast<float4*>(Cs + row * DS + (n4 - 144)) = v;
        }
    }
}

// ---------------------------------------------------------------------------
// K5a: scan pass A — per (b, chunk, channel): P = prod(dA), hp with h_in=0.
// ---------------------------------------------------------------------------
__global__ __launch_bounds__(128) void k5a(
    const float* __restrict__ dt, const float* __restrict__ u,
    const float* __restrict__ Bsb, const float* __restrict__ alog,
    float* __restrict__ P, float* __restrict__ HP)
{
    const int bk = blockIdx.x;          // b*NC + k
    const int b = bk / NC, k = bk - b * NC;
    const int c = threadIdx.x;
    float As[DS];
    #pragma unroll
    for (int s = 0; s < DS; ++s) As[s] = -__expf(alog[c * DS + s]);
    float Pp[DS], hp[DS];
    #pragma unroll
    for (int s = 0; s < DS; ++s) { Pp[s] = 1.f; hp[s] = 0.f; }

    const int l0 = k * CL;
    for (int i = 0; i < CL; ++i) {
        const int row = b * L_ + l0 + i;
        float dtv = dt[row * DI + c];
        float uv = u[row * DI + c];
        float dtu = dtv * uv;
        const float4* Bq = reinterpret_cast<const float4*>(Bsb + row * DS);
        float Bv[DS];
        #pragma unroll
        for (int q = 0; q < 4; ++q)
            *reinterpret_cast<float4*>(&Bv[q * 4]) = Bq[q];
        #pragma unroll
        for (int s = 0; s < DS; ++s) {
            float dA = __expf(dtv * As[s]);
            hp[s] = dA * hp[s] + dtu * Bv[s];
            Pp[s] *= dA;
        }
    }
    float* Pd = P + bk * 2048 + c * DS;
    float* Hd = HP + bk * 2048 + c * DS;
    #pragma unroll
    for (int q = 0; q < 4; ++q) {
        reinterpret_cast<float4*>(Pd)[q] = *reinterpret_cast<float4*>(&Pp[q * 4]);
        reinterpret_cast<float4*>(Hd)[q] = *reinterpret_cast<float4*>(&hp[q * 4]);
    }
}

// ---------------------------------------------------------------------------
// K5b: serial scan over NC chunk carries; carry-in written in-place over P.
// ---------------------------------------------------------------------------
__global__ __launch_bounds__(256) void k5b(
    float* __restrict__ P, const float* __restrict__ HP)
{
    const int t = blockIdx.x * 256 + threadIdx.x;   // 0..8191
    const int b = t >> 11, cs = t & 2047;
    float carry = 0.f;
    for (int k = 0; k < NC; ++k) {
        const int idx = (b * NC + k) * 2048 + cs;
        float p = P[idx];
        float hp = HP[idx];
        P[idx] = carry;                 // carry-in for chunk k
        carry = hp + p * carry;
    }
}

// ---------------------------------------------------------------------------
// K5c: replay with h_in (from P), y = (h·C + u*D) * silu(z), in-place over u.
// ---------------------------------------------------------------------------
__global__ __launch_bounds__(128) void k5c(
    const float* __restrict__ dt, float* __restrict__ u,
    const float* __restrict__ Bsb, const float* __restrict__ Csb,
    const float* __restrict__ sz, const float* __restrict__ alog,
    const float* __restrict__ Db, const float* __restrict__ HI)
{
    const int bk = blockIdx.x;
    const int b = bk / NC, k = bk - b * NC;
    const int c = threadIdx.x;
    float As[DS];
    #pragma unroll
    for (int s = 0; s < DS; ++s) As[s] = -__expf(alog[c * DS + s]);
    const float Dc = Db[c];
    float h[DS];
    const float* Hs = HI + bk * 2048 + c * DS;
    #pragma unroll
    for (int q = 0; q < 4; ++q)
        *reinterpret_cast<float4*>(&h[q * 4]) = reinterpret_cast<const float4*>(Hs)[q];

    const int l0 = k * CL;
    for (int i = 0; i < CL; ++i) {
        const int row = b * L_ + l0 + i;
        float dtv = dt[row * DI + c];
        float uv = u[row * DI + c];
        float szv = sz[row * DI + c];
        float dtu = dtv * uv;
        const float4* Bq = reinterpret_cast<const float4*>(Bsb + row * DS);
        const float4* Cq = reinterpret_cast<const float4*>(Csb + row * DS);
        float Bv[DS], Cv[DS];
        #pragma unroll
        for (int q = 0; q < 4; ++q) {
            *reinterpret_cast<float4*>(&Bv[q * 4]) = Bq[q];
            *reinterpret_cast<float4*>(&Cv[q * 4]) = Cq[q];
        }
        float ya[4] = {0.f, 0.f, 0.f, 0.f};
        #pragma unroll
        for (int s = 0; s < DS; ++s) {
            float dA = __expf(dtv * As[s]);
            h[s] = dA * h[s] + dtu * Bv[s];
            ya[s & 3] += h[s] * Cv[s];
        }
        float yv = (ya[0] + ya[1]) + (ya[2] + ya[3]);
        u[row * DI + c] = (yv + uv * Dc) * szv;   // in-place y
    }
}

// ---------------------------------------------------------------------------
// G6: out_proj GEMM + residual (+2*seq) + LDS-transposed NCHW store.
// 64 rows/block, N=64, K=128. thread: n4=(t&15)*4, r4=(t>>4)*4 -> acc[4][4].
// ---------------------------------------------------------------------------
__global__ __launch_bounds__(256) void g6_outproj(
    const float* __restrict__ yc, const float* __restrict__ W6t,
    const float* __restrict__ seq, float* __restrict__ out)
{
    __shared__ float smem[64 * 132];    // xL[64][132]; reused as yT[64][68]
    const int row0 = blockIdx.x * 64;
    const int t = threadIdx.x;

    for (int idx = t; idx < 2048; idx += 256) {
        int r = idx >> 5, kq = (idx & 31) * 4;
        float4 v = *reinterpret_cast<const float4*>(yc + (row0 + r) * DI + kq);
        *reinterpret_cast<float4*>(&smem[r * 132 + kq]) = v;
    }
    __syncthreads();

    const int n4 = (t & 15) * 4;
    const int r4 = (t >> 4) * 4;
    float acc[4][4];
    #pragma unroll
    for (int j = 0; j < 4; ++j)
        acc[j][0] = acc[j][1] = acc[j][2] = acc[j][3] = 0.f;

    for (int k = 0; k < 128; ++k) {
        float4 w = *reinterpret_cast<const float4*>(W6t + k * 64 + n4);
        #pragma unroll
        for (int j = 0; j < 4; ++j) {
            float xv = smem[(r4 + j) * 132 + k];
            acc[j][0] += xv * w.x; acc[j][1] += xv * w.y;
            acc[j][2] += xv * w.z; acc[j][3] += xv * w.w;
        }
    }
    __syncthreads();                    // done reading xL

    // residual + transpose into yT[n][r] (stride 68)
    #pragma unroll
    for (int j = 0; j < 4; ++j) {
        int row = row0 + r4 + j;
        float4 s = *reinterpret_cast<const float4*>(seq + row * 64 + n4);
        smem[(n4 + 0) * 68 + r4 + j] = acc[j][0] + 2.f * s.x;
        smem[(n4 + 1) * 68 + r4 + j] = acc[j][1] + 2.f * s.y;
        smem[(n4 + 2) * 68 + r4 + j] = acc[j][2] + 2.f * s.z;
        smem[(n4 + 3) * 68 + r4 + j] = acc[j][3] + 2.f * s.w;
    }
    __syncthreads();

    // store: thread t -> n = t/4, l-quarter = (t&3)*16; 256B runs per n
    const int n = t >> 2;
    const int lq = (t & 3) * 16;
    const int b = row0 / L_;
    const int l0 = row0 % L_;
    float* op = out + (b * 64 + n) * L_ + l0 + lq;
    #pragma unroll
    for (int q = 0; q < 4; ++q) {
        float4 v = *reinterpret_cast<float4*>(&smem[n * 68 + lq + q * 4]);
        *reinterpret_cast<float4*>(op + q * 4) = v;
    }
}

extern "C" void kernel_launch(void* const* d_in, const int* in_sizes, int n_in,
                              void* d_out, int out_size, void* d_ws, size_t ws_size,
                              hipStream_t stream)
{
    const float* x    = (const float*)d_in[0];
    const float* cw   = (const float*)d_in[1];
    const float* cb   = (const float*)d_in[2];
    const float* g    = (const float*)d_in[3];
    const float* be   = (const float*)d_in[4];
    const float* ipw  = (const float*)d_in[5];
    const float* c1w  = (const float*)d_in[6];
    const float* c1b  = (const float*)d_in[7];
    const float* xpw  = (const float*)d_in[8];
    const float* dtw  = (const float*)d_in[9];
    const float* dtb  = (const float*)d_in[10];
    const float* alog = (const float*)d_in[11];
    const float* Db   = (const float*)d_in[12];
    const float* opw  = (const float*)d_in[13];

    float* ws  = (float*)d_ws;
    float* seq = ws;                      // 2,359,296
    float* nrm = seq + 2359296;           // 2,359,296 ; reused: Bs, Cs
    float* xm  = nrm + 2359296;           // 4,718,592 ; reused: P, HP
    float* sz  = xm + 4718592;            // 4,718,592
    float* u   = sz + 4718592;            // 4,718,592 ; k5c writes y in-place
    float* dt  = u + 4718592;             // 4,718,592
    float* W2t = dt + 4718592;            // 16,384
    float* Wct = W2t + 16384;             // 20,480
    float* W6t = Wct + 20480;             // 8,192
    // aliases (lifetimes disjoint with hosts)
    float* Bs  = nrm;                     // 589,824  (after g2)
    float* Cs  = nrm + 589824;            // 589,824
    float* P   = xm;                      // 2,097,152 (after k3; HI in-place)
    float* HP  = xm + 2097152;            // 2,097,152

    k0_prep   <<<176, 256, 0, stream>>>(ipw, xpw, dtw, opw, W2t, Wct, W6t);
    k1_conv_ln<<<2304, 256, 0, stream>>>(x, cw, cb, g, be, seq, nrm);
    g2_inproj <<<576, 256, 0, stream>>>(nrm, W2t, xm, sz);
    k3_dwconv <<<4608, 256, 0, stream>>>(xm, c1w, c1b, u);
    g4_xproj  <<<576, 320, 0, stream>>>(u, Wct, dtb, dt, Bs, Cs);
    k5a       <<<B_ * NC, 128, 0, stream>>>(dt, u, Bs, alog, P, HP);
    k5b       <<<32, 256, 0, stream>>>(P, HP);
    k5c       <<<B_ * NC, 128, 0, stream>>>(dt, u, Bs, Cs, sz, alog, Db, P);
    g6_outproj<<<576, 256, 0, stream>>>(u, W6t, seq, (float*)d_out);
}

// Round 4
// 312.286 us; speedup vs baseline: 2.7460x; 1.4332x over previous
//
#include <hip/hip_runtime.h>
#include <hip/hip_bf16.h>

// Problem constants
#define B_   4
#define CIN  32
#define HIN  192
#define WIN  192
#define HO   96
#define WO   96
#define L_   9216      // HO*WO
#define C_   64        // DIM
#define DI   128       // d_inner
#define DS   16        // d_state
#define NC   256       // scan chunks
#define CL   36        // chunk length = L_/NC

typedef unsigned short u16t;
typedef unsigned int   u32t;
typedef short s16x8 __attribute__((ext_vector_type(8)));
typedef float f32x4 __attribute__((ext_vector_type(4)));

__device__ __forceinline__ u16t f2b(float f) {   // fp32 -> bf16 bits, RNE
    u32t u = __float_as_uint(f);
    return (u16t)((u + 0x7fffu + ((u >> 16) & 1u)) >> 16);
}

// ---------------------------------------------------------------------------
// K0: prep — transpose weights; fuse dt_proj@x_proj[:4]; pack conv W to bf16
// MFMA B-fragments.
//   W2t[64][256]  : W2t[k][n] = in_proj_w[n][k]
//   Wct[128][160] : fused x_proj/dt_proj, k-major
//   W6t[128][64]  : W6t[k][n] = out_proj_w[n][k]
//   Bp[kt][nt][lane][8] : bf16 of conv_w[n=nt*16+(ln&15)][k=kt*32+(ln>>4)*8+j]
// ---------------------------------------------------------------------------
__global__ __launch_bounds__(256) void k0_prep(
    const float* __restrict__ ipw, const float* __restrict__ xpw,
    const float* __restrict__ dtw, const float* __restrict__ opw,
    const float* __restrict__ cw,
    float* __restrict__ W2t, float* __restrict__ Wct, float* __restrict__ W6t,
    u16t* __restrict__ Bp)
{
    int i = blockIdx.x * 256 + threadIdx.x;
    if (i < 16384) {
        int k = i >> 8, n = i & 255;
        W2t[i] = ipw[n * 64 + k];
    } else if (i < 16384 + 20480) {
        int j = i - 16384;
        int k = j / 160, n = j - k * 160;
        float v;
        if (n < 128) {
            v = dtw[n * 4 + 0] * xpw[0 * 128 + k] + dtw[n * 4 + 1] * xpw[1 * 128 + k]
              + dtw[n * 4 + 2] * xpw[2 * 128 + k] + dtw[n * 4 + 3] * xpw[3 * 128 + k];
        } else if (n < 144) {
            v = xpw[(4 + n - 128) * 128 + k];
        } else {
            v = xpw[(20 + n - 144) * 128 + k];
        }
        Wct[j] = v;
    } else if (i < 16384 + 20480 + 8192) {
        int j = i - 16384 - 20480;
        int k = j >> 6, n = j & 63;
        W6t[j] = opw[n * 128 + k];
    } else if (i < 45056 + 32768) {
        int j = i - 45056;
        int e  = j & 7;
        int ln = (j >> 3) & 63;
        int nt = (j >> 9) & 3;
        int kt = j >> 11;
        int n  = nt * 16 + (ln & 15);
        int k  = kt * 32 + (ln >> 4) * 8 + e;
        Bp[j] = f2b(cw[n * 512 + k]);
    }
}

// ---------------------------------------------------------------------------
// K1: ReflectionPad(1)+Conv2d(32->64,k4,s2)+bias+LayerNorm as bf16 MFMA
// implicit GEMM. Block = 64 pixels (4 waves x 16), N=64, K=512 in 4 chunks
// of 128 (8 input channels). fp32 accum; LN fused in epilogue.
// ---------------------------------------------------------------------------
__global__ __launch_bounds__(256) void k1_conv_ln(
    const float* __restrict__ x, const u16t* __restrict__ Bp,
    const float* __restrict__ cb, const float* __restrict__ g,
    const float* __restrict__ be,
    float* __restrict__ seq, float* __restrict__ nrm)
{
    __shared__ u16t At[64 * 136];       // 64 pixels x 128 k (bf16), +8 pad
    const int t = threadIdx.x;
    const int pix0 = blockIdx.x * 64;
    const int b = pix0 / L_;
    const int l0 = pix0 % L_;
    const int wave = t >> 6, ln = t & 63;
    const int quad = ln >> 4, col = ln & 15;

    // staging role: fixed (ci_local, kh, kw) column, 32 pixels (stride 2)
    const int kk = t & 127;
    const int m0 = t >> 7;
    const int kh = (kk >> 2) & 3, kw = kk & 3, cil = kk >> 4;

    f32x4 acc[4];
    #pragma unroll
    for (int nt = 0; nt < 4; ++nt) acc[nt] = (f32x4){0.f, 0.f, 0.f, 0.f};

    const u16t* arow = &At[(wave * 16 + col) * 136 + quad * 8];

    for (int cc = 0; cc < 4; ++cc) {
        __syncthreads();                // protect At from previous chunk's readers
        const float* xb = x + (b * CIN + cc * 8 + cil) * (HIN * WIN);
        #pragma unroll 4
        for (int j = 0; j < 32; ++j) {
            int m = m0 + 2 * j;
            int l = l0 + m;
            int oh = l / WO, ow = l - oh * WO;
            int ih = 2 * oh + kh - 1; ih = ih < 0 ? 1 : (ih >= HIN ? 2 * HIN - 2 - ih : ih);
            int iw = 2 * ow + kw - 1; iw = iw < 0 ? 1 : (iw >= WIN ? 2 * WIN - 2 - iw : iw);
            At[m * 136 + kk] = f2b(xb[ih * WIN + iw]);
        }
        __syncthreads();

        #pragma unroll
        for (int ktl = 0; ktl < 4; ++ktl) {
            s16x8 a = *reinterpret_cast<const s16x8*>(arow + ktl * 32);
            const u16t* bpb = Bp + (cc * 4 + ktl) * 2048 + ln * 8;
            #pragma unroll
            for (int nt = 0; nt < 4; ++nt) {
                s16x8 bf = *reinterpret_cast<const s16x8*>(bpb + nt * 512);
                acc[nt] = __builtin_amdgcn_mfma_f32_16x16x32_bf16(a, bf, acc[nt], 0, 0, 0);
            }
        }
    }

    // epilogue: +bias, LayerNorm over the 64 channels, store seq & nrm
    float gv[4], bv[4], cbv[4];
    #pragma unroll
    for (int nt = 0; nt < 4; ++nt) {
        gv[nt] = g[nt * 16 + col];
        bv[nt] = be[nt * 16 + col];
        cbv[nt] = cb[nt * 16 + col];
    }
    #pragma unroll
    for (int r = 0; r < 4; ++r) {
        float v0 = acc[0][r] + cbv[0];
        float v1 = acc[1][r] + cbv[1];
        float v2 = acc[2][r] + cbv[2];
        float v3 = acc[3][r] + cbv[3];
        float s1 = (v0 + v1) + (v2 + v3);
        float s2 = (v0 * v0 + v1 * v1) + (v2 * v2 + v3 * v3);
        #pragma unroll
        for (int mk = 1; mk <= 8; mk <<= 1) {
            s1 += __shfl_xor(s1, mk);
            s2 += __shfl_xor(s2, mk);
        }
        float mu = s1 * (1.0f / 64.0f);
        float var = s2 * (1.0f / 64.0f) - mu * mu;
        float rs = rsqrtf(var + 1e-5f);
        int pix = pix0 + wave * 16 + quad * 4 + r;
        float* sp = seq + pix * 64 + col;
        float* np = nrm + pix * 64 + col;
        sp[0]  = v0; sp[16] = v1; sp[32] = v2; sp[48] = v3;
        np[0]  = (v0 - mu) * rs * gv[0] + bv[0];
        np[16] = (v1 - mu) * rs * gv[1] + bv[1];
        np[32] = (v2 - mu) * rs * gv[2] + bv[2];
        np[48] = (v3 - mu) * rs * gv[3] + bv[3];
    }
}

// ---------------------------------------------------------------------------
// G2: in_proj GEMM. 64 rows/block, N=256, K=64. W2t streamed from L2.
// ---------------------------------------------------------------------------
__global__ __launch_bounds__(256) void g2_inproj(
    const float* __restrict__ nrm, const float* __restrict__ W2t,
    float* __restrict__ xm, float* __restrict__ sz)
{
    __shared__ float xL[64][68];
    const int row0 = blockIdx.x * 64;
    const int t = threadIdx.x;

    for (int idx = t; idx < 1024; idx += 256) {
        int r = idx >> 4, kq = (idx & 15) * 4;
        float4 v = *reinterpret_cast<const float4*>(nrm + (row0 + r) * 64 + kq);
        *reinterpret_cast<float4*>(&xL[r][kq]) = v;
    }
    __syncthreads();

    const int n4 = (t & 63) * 4;
    const int r16 = (t >> 6) * 16;
    float acc[16][4];
    #pragma unroll
    for (int j = 0; j < 16; ++j)
        acc[j][0] = acc[j][1] = acc[j][2] = acc[j][3] = 0.f;

    for (int k = 0; k < 64; ++k) {
        float4 w = *reinterpret_cast<const float4*>(W2t + k * 256 + n4);
        #pragma unroll
        for (int j = 0; j < 16; ++j) {
            float xv = xL[r16 + j][k];
            acc[j][0] += xv * w.x; acc[j][1] += xv * w.y;
            acc[j][2] += xv * w.z; acc[j][3] += xv * w.w;
        }
    }

    #pragma unroll
    for (int j = 0; j < 16; ++j) {
        int row = row0 + r16 + j;
        float4 v = {acc[j][0], acc[j][1], acc[j][2], acc[j][3]};
        if (n4 < 128) {
            *reinterpret_cast<float4*>(xm + row * DI + n4) = v;
        } else {
            v.x = v.x / (1.f + __expf(-v.x));
            v.y = v.y / (1.f + __expf(-v.y));
            v.z = v.z / (1.f + __expf(-v.z));
            v.w = v.w / (1.f + __expf(-v.w));
            *reinterpret_cast<float4*>(sz + row * DI + (n4 - 128)) = v;
        }
    }
}

// ---------------------------------------------------------------------------
// K3: causal depthwise conv1d (k=4) + bias + SiLU. 4 outputs per thread.
// ---------------------------------------------------------------------------
__global__ __launch_bounds__(256) void k3_dwconv(
    const float* __restrict__ xm, const float* __restrict__ w,
    const float* __restrict__ bia, float* __restrict__ u)
{
    const int gid = blockIdx.x * 256 + threadIdx.x;
    const int c = gid & 127;
    const int g = gid >> 7;
    const int bl0 = g * 4;
    const int l0 = bl0 % L_;

    float w0 = w[c * 4 + 0], w1 = w[c * 4 + 1];
    float w2 = w[c * 4 + 2], w3 = w[c * 4 + 3];
    float bv = bia[c];

    float xv[7];
    if (l0 == 0) { xv[0] = xv[1] = xv[2] = 0.f; }
    else {
        xv[0] = xm[(bl0 - 3) * DI + c];
        xv[1] = xm[(bl0 - 2) * DI + c];
        xv[2] = xm[(bl0 - 1) * DI + c];
    }
    #pragma unroll
    for (int j = 0; j < 4; ++j) xv[3 + j] = xm[(bl0 + j) * DI + c];

    #pragma unroll
    for (int j = 0; j < 4; ++j) {
        float a = bv + xv[j] * w0 + xv[j + 1] * w1 + xv[j + 2] * w2 + xv[j + 3] * w3;
        u[(bl0 + j) * DI + c] = a / (1.f + __expf(-a));
    }
}

// ---------------------------------------------------------------------------
// G4: fused x_proj + dt_proj GEMM. 64 rows/block, N=160 (dt128|B16|C16), K=128.
// ---------------------------------------------------------------------------
__global__ __launch_bounds__(320) void g4_xproj(
    const float* __restrict__ u, const float* __restrict__ Wct,
    const float* __restrict__ dtb,
    float* __restrict__ dt, float* __restrict__ Bs, float* __restrict__ Cs)
{
    __shared__ float xL[64][132];
    const int row0 = blockIdx.x * 64;
    const int t = threadIdx.x;

    for (int idx = t; idx < 2048; idx += 320) {
        int r = idx >> 5, kq = (idx & 31) * 4;
        float4 v = *reinterpret_cast<const float4*>(u + (row0 + r) * DI + kq);
        *reinterpret_cast<float4*>(&xL[r][kq]) = v;
    }
    __syncthreads();

    const int nt = t % 40;
    const int n4 = nt * 4;
    const int r8 = (t / 40) * 8;
    float acc[8][4];
    #pragma unroll
    for (int j = 0; j < 8; ++j)
        acc[j][0] = acc[j][1] = acc[j][2] = acc[j][3] = 0.f;

    for (int k = 0; k < 128; ++k) {
        float4 w = *reinterpret_cast<const float4*>(Wct + k * 160 + n4);
        #pragma unroll
        for (int j = 0; j < 8; ++j) {
            float xv = xL[r8 + j][k];
            acc[j][0] += xv * w.x; acc[j][1] += xv * w.y;
            acc[j][2] += xv * w.z; acc[j][3] += xv * w.w;
        }
    }

    if (n4 < 128) {
        float4 db = *reinterpret_cast<const float4*>(dtb + n4);
        #pragma unroll
        for (int j = 0; j < 8; ++j) {
            int row = row0 + r8 + j;
            float4 v = {acc[j][0] + db.x, acc[j][1] + db.y,
                        acc[j][2] + db.z, acc[j][3] + db.w};
            v.x = v.x > 20.f ? v.x : log1pf(__expf(v.x));
            v.y = v.y > 20.f ? v.y : log1pf(__expf(v.y));
            v.z = v.z > 20.f ? v.z : log1pf(__expf(v.z));
            v.w = v.w > 20.f ? v.w : log1pf(__expf(v.w));
            *reinterpret_cast<float4*>(dt + row * DI + n4) = v;
        }
    } else if (n4 < 144) {
        #pragma unroll
        for (int j = 0; j < 8; ++j) {
            int row = row0 + r8 + j;
            float4 v = {acc[j][0], acc[j][1], acc[j][2], acc[j][3]};
            *reinterpret_cast<float4*>(Bs + row * DS + (n4 - 128)) = v;
        }
    } else {
        #pragma unroll
        for (int j = 0; j < 8; ++j) {
            int row = row0 + r8 + j;
            float4 v = {acc[j][0], acc[j][1], acc[j][2], acc[j][3]};
            *reinterpret_cast<float4*>(Cs + row * DS + (n4 - 144)) = v;
        }
    }
}

// ---------------------------------------------------------------------------
// K5a: scan pass A — per (b, chunk, channel): P = prod(dA), hp with h_in=0.
// ---------------------------------------------------------------------------
__global__ __launch_bounds__(128) void k5a(
    const float* __restrict__ dt, const float* __restrict__ u,
    const float* __restrict__ Bsb, const float* __restrict__ alog,
    float* __restrict__ P, float* __restrict__ HP)
{
    const int bk = blockIdx.x;
    const int b = bk / NC, k = bk - b * NC;
    const int c = threadIdx.x;
    float As[DS];
    #pragma unroll
    for (int s = 0; s < DS; ++s) As[s] = -__expf(alog[c * DS + s]);
    float Pp[DS], hp[DS];
    #pragma unroll
    for (int s = 0; s < DS; ++s) { Pp[s] = 1.f; hp[s] = 0.f; }

    const int l0 = k * CL;
    for (int i = 0; i < CL; ++i) {
        const int row = b * L_ + l0 + i;
        float dtv = dt[row * DI + c];
        float uv = u[row * DI + c];
        float dtu = dtv * uv;
        const float4* Bq = reinterpret_cast<const float4*>(Bsb + row * DS);
        float Bv[DS];
        #pragma unroll
        for (int q = 0; q < 4; ++q)
            *reinterpret_cast<float4*>(&Bv[q * 4]) = Bq[q];
        #pragma unroll
        for (int s = 0; s < DS; ++s) {
            float dA = __expf(dtv * As[s]);
            hp[s] = dA * hp[s] + dtu * Bv[s];
            Pp[s] *= dA;
        }
    }
    float* Pd = P + bk * 2048 + c * DS;
    float* Hd = HP + bk * 2048 + c * DS;
    #pragma unroll
    for (int q = 0; q < 4; ++q) {
        reinterpret_cast<float4*>(Pd)[q] = *reinterpret_cast<float4*>(&Pp[q * 4]);
        reinterpret_cast<float4*>(Hd)[q] = *reinterpret_cast<float4*>(&hp[q * 4]);
    }
}

// ---------------------------------------------------------------------------
// K5b: serial scan over NC chunk carries; carry-in written in-place over P.
// ---------------------------------------------------------------------------
__global__ __launch_bounds__(256) void k5b(
    float* __restrict__ P, const float* __restrict__ HP)
{
    const int t = blockIdx.x * 256 + threadIdx.x;
    const int b = t >> 11, cs = t & 2047;
    float carry = 0.f;
    for (int k = 0; k < NC; ++k) {
        const int idx = (b * NC + k) * 2048 + cs;
        float p = P[idx];
        float hp = HP[idx];
        P[idx] = carry;
        carry = hp + p * carry;
    }
}

// ---------------------------------------------------------------------------
// K5c: replay with h_in (from P), y = (h·C + u*D) * silu(z), in-place over u.
// ---------------------------------------------------------------------------
__global__ __launch_bounds__(128) void k5c(
    const float* __restrict__ dt, float* __restrict__ u,
    const float* __restrict__ Bsb, const float* __restrict__ Csb,
    const float* __restrict__ sz, const float* __restrict__ alog,
    const float* __restrict__ Db, const float* __restrict__ HI)
{
    const int bk = blockIdx.x;
    const int b = bk / NC, k = bk - b * NC;
    const int c = threadIdx.x;
    float As[DS];
    #pragma unroll
    for (int s = 0; s < DS; ++s) As[s] = -__expf(alog[c * DS + s]);
    const float Dc = Db[c];
    float h[DS];
    const float* Hs = HI + bk * 2048 + c * DS;
    #pragma unroll
    for (int q = 0; q < 4; ++q)
        *reinterpret_cast<float4*>(&h[q * 4]) = reinterpret_cast<const float4*>(Hs)[q];

    const int l0 = k * CL;
    for (int i = 0; i < CL; ++i) {
        const int row = b * L_ + l0 + i;
        float dtv = dt[row * DI + c];
        float uv = u[row * DI + c];
        float szv = sz[row * DI + c];
        float dtu = dtv * uv;
        const float4* Bq = reinterpret_cast<const float4*>(Bsb + row * DS);
        const float4* Cq = reinterpret_cast<const float4*>(Csb + row * DS);
        float Bv[DS], Cv[DS];
        #pragma unroll
        for (int q = 0; q < 4; ++q) {
            *reinterpret_cast<float4*>(&Bv[q * 4]) = Bq[q];
            *reinterpret_cast<float4*>(&Cv[q * 4]) = Cq[q];
        }
        float ya[4] = {0.f, 0.f, 0.f, 0.f};
        #pragma unroll
        for (int s = 0; s < DS; ++s) {
            float dA = __expf(dtv * As[s]);
            h[s] = dA * h[s] + dtu * Bv[s];
            ya[s & 3] += h[s] * Cv[s];
        }
        float yv = (ya[0] + ya[1]) + (ya[2] + ya[3]);
        u[row * DI + c] = (yv + uv * Dc) * szv;
    }
}

// ---------------------------------------------------------------------------
// G6: out_proj GEMM + residual (+2*seq) + LDS-transposed NCHW store.
// ---------------------------------------------------------------------------
__global__ __launch_bounds__(256) void g6_outproj(
    const float* __restrict__ yc, const float* __restrict__ W6t,
    const float* __restrict__ seq, float* __restrict__ out)
{
    __shared__ float smem[64 * 132];
    const int row0 = blockIdx.x * 64;
    const int t = threadIdx.x;

    for (int idx = t; idx < 2048; idx += 256) {
        int r = idx >> 5, kq = (idx & 31) * 4;
        float4 v = *reinterpret_cast<const float4*>(yc + (row0 + r) * DI + kq);
        *reinterpret_cast<float4*>(&smem[r * 132 + kq]) = v;
    }
    __syncthreads();

    const int n4 = (t & 15) * 4;
    const int r4 = (t >> 4) * 4;
    float acc[4][4];
    #pragma unroll
    for (int j = 0; j < 4; ++j)
        acc[j][0] = acc[j][1] = acc[j][2] = acc[j][3] = 0.f;

    for (int k = 0; k < 128; ++k) {
        float4 w = *reinterpret_cast<const float4*>(W6t + k * 64 + n4);
        #pragma unroll
        for (int j = 0; j < 4; ++j) {
            float xv = smem[(r4 + j) * 132 + k];
            acc[j][0] += xv * w.x; acc[j][1] += xv * w.y;
            acc[j][2] += xv * w.z; acc[j][3] += xv * w.w;
        }
    }
    __syncthreads();

    #pragma unroll
    for (int j = 0; j < 4; ++j) {
        int row = row0 + r4 + j;
        float4 s = *reinterpret_cast<const float4*>(seq + row * 64 + n4);
        smem[(n4 + 0) * 68 + r4 + j] = acc[j][0] + 2.f * s.x;
        smem[(n4 + 1) * 68 + r4 + j] = acc[j][1] + 2.f * s.y;
        smem[(n4 + 2) * 68 + r4 + j] = acc[j][2] + 2.f * s.z;
        smem[(n4 + 3) * 68 + r4 + j] = acc[j][3] + 2.f * s.w;
    }
    __syncthreads();

    const int n = t >> 2;
    const int lq = (t & 3) * 16;
    const int b = row0 / L_;
    const int l0 = row0 % L_;
    float* op = out + (b * 64 + n) * L_ + l0 + lq;
    #pragma unroll
    for (int q = 0; q < 4; ++q) {
        float4 v = *reinterpret_cast<float4*>(&smem[n * 68 + lq + q * 4]);
        *reinterpret_cast<float4*>(op + q * 4) = v;
    }
}

extern "C" void kernel_launch(void* const* d_in, const int* in_sizes, int n_in,
                              void* d_out, int out_size, void* d_ws, size_t ws_size,
                              hipStream_t stream)
{
    const float* x    = (const float*)d_in[0];
    const float* cw   = (const float*)d_in[1];
    const float* cb   = (const float*)d_in[2];
    const float* g    = (const float*)d_in[3];
    const float* be   = (const float*)d_in[4];
    const float* ipw  = (const float*)d_in[5];
    const float* c1w  = (const float*)d_in[6];
    const float* c1b  = (const float*)d_in[7];
    const float* xpw  = (const float*)d_in[8];
    const float* dtw  = (const float*)d_in[9];
    const float* dtb  = (const float*)d_in[10];
    const float* alog = (const float*)d_in[11];
    const float* Db   = (const float*)d_in[12];
    const float* opw  = (const float*)d_in[13];

    float* ws  = (float*)d_ws;
    float* seq = ws;                      // 2,359,296
    float* nrm = seq + 2359296;           // 2,359,296 ; reused: Bs, Cs
    float* xm  = nrm + 2359296;           // 4,718,592 ; reused: P, HP
    float* sz  = xm + 4718592;            // 4,718,592
    float* u   = sz + 4718592;            // 4,718,592 ; k5c writes y in-place
    float* dt  = u + 4718592;             // 4,718,592
    float* W2t = dt + 4718592;            // 16,384
    float* Wct = W2t + 16384;             // 20,480
    float* W6t = Wct + 20480;             // 8,192
    u16t*  Bp  = (u16t*)(W6t + 8192);     // 32,768 u16 (16,384 floats)
    // aliases (lifetimes disjoint with hosts)
    float* Bs  = nrm;                     // 589,824  (after g2)
    float* Cs  = nrm + 589824;            // 589,824
    float* P   = xm;                      // 2,097,152 (after k3; HI in-place)
    float* HP  = xm + 2097152;            // 2,097,152

    k0_prep   <<<304, 256, 0, stream>>>(ipw, xpw, dtw, opw, cw, W2t, Wct, W6t, Bp);
    k1_conv_ln<<<576, 256, 0, stream>>>(x, Bp, cb, g, be, seq, nrm);
    g2_inproj <<<576, 256, 0, stream>>>(nrm, W2t, xm, sz);
    k3_dwconv <<<4608, 256, 0, stream>>>(xm, c1w, c1b, u);
    g4_xproj  <<<576, 320, 0, stream>>>(u, Wct, dtb, dt, Bs, Cs);
    k5a       <<<B_ * NC, 128, 0, stream>>>(dt, u, Bs, alog, P, HP);
    k5b       <<<32, 256, 0, stream>>>(P, HP);
    k5c       <<<B_ * NC, 128, 0, stream>>>(dt, u, Bs, Cs, sz, alog, Db, P);
    g6_outproj<<<576, 256, 0, stream>>>(u, W6t, seq, (float*)d_out);
}

// Round 5
// 261.538 us; speedup vs baseline: 3.2788x; 1.1940x over previous
//
#include <hip/hip_runtime.h>
#include <hip/hip_bf16.h>

// Problem constants
#define B_   4
#define CIN  32
#define HIN  192
#define WIN  192
#define HO   96
#define WO   96
#define L_   9216      // HO*WO
#define C_   64        // DIM
#define DI   128       // d_inner
#define DS   16        // d_state
#define NC   256       // scan chunks
#define CL   36        // chunk length = L_/NC

typedef unsigned short u16t;
typedef unsigned int   u32t;
typedef short s16x8 __attribute__((ext_vector_type(8)));
typedef float f32x4 __attribute__((ext_vector_type(4)));

__device__ __forceinline__ u16t f2b(float f) {   // fp32 -> bf16 bits, RNE
    u32t u = __float_as_uint(f);
    return (u16t)((u + 0x7fffu + ((u >> 16) & 1u)) >> 16);
}
__device__ __forceinline__ float b2f(u16t h) { return __uint_as_float(((u32t)h) << 16); }
__device__ __forceinline__ void split2(float v, u16t& hi, u16t& lo) {
    hi = f2b(v);
    lo = f2b(v - b2f(hi));
}

#define MFMA16(a, b, c) __builtin_amdgcn_mfma_f32_16x16x32_bf16((a), (b), (c), 0, 0, 0)

// ---------------------------------------------------------------------------
// K0: prep — pack all projection weights into bf16 hi/lo MFMA B-fragments.
// Fragment layout (16x16x32): B[n=nt*16+(ln&15)][k=kt*32+(ln>>4)*8+e]
//   W2p[kt2][nt16][hl2][ln64][e8]  : in_proj_w (n<256, k<64)
//   Wcp[kt4][nt10][hl2][ln64][e8]  : fused x_proj/dt_proj (n<160, k<128)
//   W6p[kt4][nt4][hl2][ln64][e8]   : out_proj_w (n<64, k<128)
//   Bp [kt16][nt4][ln64][e8]       : conv_w bf16 (single, k1 unchanged)
// ---------------------------------------------------------------------------
__global__ __launch_bounds__(256) void k0_prep(
    const float* __restrict__ ipw, const float* __restrict__ xpw,
    const float* __restrict__ dtw, const float* __restrict__ opw,
    const float* __restrict__ cw,
    u16t* __restrict__ W2p, u16t* __restrict__ Wcp, u16t* __restrict__ W6p,
    u16t* __restrict__ Bp)
{
    int i = blockIdx.x * 256 + threadIdx.x;
    if (i < 32768) {
        int e = i & 7, ln = (i >> 3) & 63, hl = (i >> 9) & 1;
        int nt = (i >> 10) & 15, kt = i >> 14;
        int n = nt * 16 + (ln & 15), k = kt * 32 + (ln >> 4) * 8 + e;
        u16t hi, lo; split2(ipw[n * 64 + k], hi, lo);
        W2p[i] = hl ? lo : hi;
    } else if (i < 32768 + 40960) {
        int j = i - 32768;
        int e = j & 7, ln = (j >> 3) & 63, hl = (j >> 9) & 1;
        int r = j >> 10; int nt = r % 10, kt = r / 10;
        int n = nt * 16 + (ln & 15), k = kt * 32 + (ln >> 4) * 8 + e;
        float v;
        if (n < 128) {
            v = dtw[n * 4 + 0] * xpw[0 * 128 + k] + dtw[n * 4 + 1] * xpw[1 * 128 + k]
              + dtw[n * 4 + 2] * xpw[2 * 128 + k] + dtw[n * 4 + 3] * xpw[3 * 128 + k];
        } else if (n < 144) {
            v = xpw[(4 + n - 128) * 128 + k];
        } else {
            v = xpw[(20 + n - 144) * 128 + k];
        }
        u16t hi, lo; split2(v, hi, lo);
        Wcp[j] = hl ? lo : hi;
    } else if (i < 32768 + 40960 + 16384) {
        int j = i - 32768 - 40960;
        int e = j & 7, ln = (j >> 3) & 63, hl = (j >> 9) & 1;
        int nt = (j >> 10) & 3, kt = j >> 12;
        int n = nt * 16 + (ln & 15), k = kt * 32 + (ln >> 4) * 8 + e;
        u16t hi, lo; split2(opw[n * 128 + k], hi, lo);
        W6p[j] = hl ? lo : hi;
    } else if (i < 32768 + 40960 + 16384 + 32768) {
        int j = i - 32768 - 40960 - 16384;
        int e = j & 7, ln = (j >> 3) & 63, nt = (j >> 9) & 3, kt = j >> 11;
        int n = nt * 16 + (ln & 15), k = kt * 32 + (ln >> 4) * 8 + e;
        Bp[j] = f2b(cw[n * 512 + k]);
    }
}

// ---------------------------------------------------------------------------
// K1: ReflectionPad(1)+Conv2d(32->64,k4,s2)+bias+LayerNorm as bf16 MFMA
// implicit GEMM (unchanged from R4 — proven).
// ---------------------------------------------------------------------------
__global__ __launch_bounds__(256) void k1_conv_ln(
    const float* __restrict__ x, const u16t* __restrict__ Bp,
    const float* __restrict__ cb, const float* __restrict__ g,
    const float* __restrict__ be,
    float* __restrict__ seq, float* __restrict__ nrm)
{
    __shared__ u16t At[64 * 136];
    const int t = threadIdx.x;
    const int pix0 = blockIdx.x * 64;
    const int b = pix0 / L_;
    const int l0 = pix0 % L_;
    const int wave = t >> 6, ln = t & 63;
    const int quad = ln >> 4, col = ln & 15;

    const int kk = t & 127;
    const int m0 = t >> 7;
    const int kh = (kk >> 2) & 3, kw = kk & 3, cil = kk >> 4;

    f32x4 acc[4];
    #pragma unroll
    for (int nt = 0; nt < 4; ++nt) acc[nt] = (f32x4){0.f, 0.f, 0.f, 0.f};

    const u16t* arow = &At[(wave * 16 + col) * 136 + quad * 8];

    for (int cc = 0; cc < 4; ++cc) {
        __syncthreads();
        const float* xb = x + (b * CIN + cc * 8 + cil) * (HIN * WIN);
        #pragma unroll 4
        for (int j = 0; j < 32; ++j) {
            int m = m0 + 2 * j;
            int l = l0 + m;
            int oh = l / WO, ow = l - oh * WO;
            int ih = 2 * oh + kh - 1; ih = ih < 0 ? 1 : (ih >= HIN ? 2 * HIN - 2 - ih : ih);
            int iw = 2 * ow + kw - 1; iw = iw < 0 ? 1 : (iw >= WIN ? 2 * WIN - 2 - iw : iw);
            At[m * 136 + kk] = f2b(xb[ih * WIN + iw]);
        }
        __syncthreads();

        #pragma unroll
        for (int ktl = 0; ktl < 4; ++ktl) {
            s16x8 a = *reinterpret_cast<const s16x8*>(arow + ktl * 32);
            const u16t* bpb = Bp + (cc * 4 + ktl) * 2048 + ln * 8;
            #pragma unroll
            for (int nt = 0; nt < 4; ++nt) {
                s16x8 bf = *reinterpret_cast<const s16x8*>(bpb + nt * 512);
                acc[nt] = MFMA16(a, bf, acc[nt]);
            }
        }
    }

    float gv[4], bv[4], cbv[4];
    #pragma unroll
    for (int nt = 0; nt < 4; ++nt) {
        gv[nt] = g[nt * 16 + col];
        bv[nt] = be[nt * 16 + col];
        cbv[nt] = cb[nt * 16 + col];
    }
    #pragma unroll
    for (int r = 0; r < 4; ++r) {
        float v0 = acc[0][r] + cbv[0];
        float v1 = acc[1][r] + cbv[1];
        float v2 = acc[2][r] + cbv[2];
        float v3 = acc[3][r] + cbv[3];
        float s1 = (v0 + v1) + (v2 + v3);
        float s2 = (v0 * v0 + v1 * v1) + (v2 * v2 + v3 * v3);
        #pragma unroll
        for (int mk = 1; mk <= 8; mk <<= 1) {
            s1 += __shfl_xor(s1, mk);
            s2 += __shfl_xor(s2, mk);
        }
        float mu = s1 * (1.0f / 64.0f);
        float var = s2 * (1.0f / 64.0f) - mu * mu;
        float rs = rsqrtf(var + 1e-5f);
        int pix = pix0 + wave * 16 + quad * 4 + r;
        float* sp = seq + pix * 64 + col;
        float* np = nrm + pix * 64 + col;
        sp[0]  = v0; sp[16] = v1; sp[32] = v2; sp[48] = v3;
        np[0]  = (v0 - mu) * rs * gv[0] + bv[0];
        np[16] = (v1 - mu) * rs * gv[1] + bv[1];
        np[32] = (v2 - mu) * rs * gv[2] + bv[2];
        np[48] = (v3 - mu) * rs * gv[3] + bv[3];
    }
}

// ---------------------------------------------------------------------------
// G2: in_proj as split-bf16 MFMA GEMM. 64 rows/block, N=256, K=64.
// ---------------------------------------------------------------------------
__global__ __launch_bounds__(256) void g2_inproj(
    const float* __restrict__ nrm, const u16t* __restrict__ W2p,
    float* __restrict__ xm, float* __restrict__ sz)
{
    __shared__ u16t Ah[64 * 72], Al[64 * 72];
    const int t = threadIdx.x;
    const int row0 = blockIdx.x * 64;

    for (int idx = t; idx < 1024; idx += 256) {
        int r = idx >> 4, kq = (idx & 15) * 4;
        float4 v = *reinterpret_cast<const float4*>(nrm + (row0 + r) * 64 + kq);
        u16t h, l;
        split2(v.x, h, l); Ah[r * 72 + kq + 0] = h; Al[r * 72 + kq + 0] = l;
        split2(v.y, h, l); Ah[r * 72 + kq + 1] = h; Al[r * 72 + kq + 1] = l;
        split2(v.z, h, l); Ah[r * 72 + kq + 2] = h; Al[r * 72 + kq + 2] = l;
        split2(v.w, h, l); Ah[r * 72 + kq + 3] = h; Al[r * 72 + kq + 3] = l;
    }
    __syncthreads();

    const int wave = t >> 6, ln = t & 63, quad = ln >> 4, col = ln & 15;
    f32x4 acc[16];
    #pragma unroll
    for (int nt = 0; nt < 16; ++nt) acc[nt] = (f32x4){0.f, 0.f, 0.f, 0.f};

    const int abase = (wave * 16 + col) * 72 + quad * 8;
    #pragma unroll
    for (int kt = 0; kt < 2; ++kt) {
        s16x8 ah = *reinterpret_cast<const s16x8*>(Ah + abase + kt * 32);
        s16x8 al = *reinterpret_cast<const s16x8*>(Al + abase + kt * 32);
        const u16t* bb = W2p + (kt * 16) * 1024 + ln * 8;
        #pragma unroll
        for (int nt = 0; nt < 16; ++nt) {
            s16x8 bh = *reinterpret_cast<const s16x8*>(bb + nt * 1024);
            s16x8 bl = *reinterpret_cast<const s16x8*>(bb + nt * 1024 + 512);
            acc[nt] = MFMA16(al, bh, acc[nt]);
            acc[nt] = MFMA16(ah, bl, acc[nt]);
            acc[nt] = MFMA16(ah, bh, acc[nt]);
        }
    }

    const int mrow = row0 + wave * 16 + quad * 4;
    #pragma unroll
    for (int nt = 0; nt < 16; ++nt) {
        int n = nt * 16 + col;
        #pragma unroll
        for (int r = 0; r < 4; ++r) {
            float v = acc[nt][r];
            if (n < 128) {
                xm[(mrow + r) * DI + n] = v;
            } else {
                sz[(mrow + r) * DI + (n - 128)] = v / (1.f + __expf(-v));
            }
        }
    }
}

// ---------------------------------------------------------------------------
// K3: causal depthwise conv1d (k=4) + bias + SiLU. 4 outputs per thread.
// ---------------------------------------------------------------------------
__global__ __launch_bounds__(256) void k3_dwconv(
    const float* __restrict__ xm, const float* __restrict__ w,
    const float* __restrict__ bia, float* __restrict__ u)
{
    const int gid = blockIdx.x * 256 + threadIdx.x;
    const int c = gid & 127;
    const int g = gid >> 7;
    const int bl0 = g * 4;
    const int l0 = bl0 % L_;

    float w0 = w[c * 4 + 0], w1 = w[c * 4 + 1];
    float w2 = w[c * 4 + 2], w3 = w[c * 4 + 3];
    float bv = bia[c];

    float xv[7];
    if (l0 == 0) { xv[0] = xv[1] = xv[2] = 0.f; }
    else {
        xv[0] = xm[(bl0 - 3) * DI + c];
        xv[1] = xm[(bl0 - 2) * DI + c];
        xv[2] = xm[(bl0 - 1) * DI + c];
    }
    #pragma unroll
    for (int j = 0; j < 4; ++j) xv[3 + j] = xm[(bl0 + j) * DI + c];

    #pragma unroll
    for (int j = 0; j < 4; ++j) {
        float a = bv + xv[j] * w0 + xv[j + 1] * w1 + xv[j + 2] * w2 + xv[j + 3] * w3;
        u[(bl0 + j) * DI + c] = a / (1.f + __expf(-a));
    }
}

// ---------------------------------------------------------------------------
// G4: fused x_proj + dt_proj as split-bf16 MFMA GEMM. 64 rows/block,
// N=160 (dt128|B16|C16), K=128. Softplus epilogue on dt columns.
// ---------------------------------------------------------------------------
__global__ __launch_bounds__(256) void g4_xproj(
    const float* __restrict__ u, const u16t* __restrict__ Wcp,
    const float* __restrict__ dtb,
    float* __restrict__ dt, float* __restrict__ Bs, float* __restrict__ Cs)
{
    __shared__ u16t Ah[64 * 136], Al[64 * 136];
    const int t = threadIdx.x;
    const int row0 = blockIdx.x * 64;

    for (int idx = t; idx < 2048; idx += 256) {
        int r = idx >> 5, kq = (idx & 31) * 4;
        float4 v = *reinterpret_cast<const float4*>(u + (row0 + r) * DI + kq);
        u16t h, l;
        split2(v.x, h, l); Ah[r * 136 + kq + 0] = h; Al[r * 136 + kq + 0] = l;
        split2(v.y, h, l); Ah[r * 136 + kq + 1] = h; Al[r * 136 + kq + 1] = l;
        split2(v.z, h, l); Ah[r * 136 + kq + 2] = h; Al[r * 136 + kq + 2] = l;
        split2(v.w, h, l); Ah[r * 136 + kq + 3] = h; Al[r * 136 + kq + 3] = l;
    }
    __syncthreads();

    const int wave = t >> 6, ln = t & 63, quad = ln >> 4, col = ln & 15;
    f32x4 acc[10];
    #pragma unroll
    for (int nt = 0; nt < 10; ++nt) acc[nt] = (f32x4){0.f, 0.f, 0.f, 0.f};

    const int abase = (wave * 16 + col) * 136 + quad * 8;
    #pragma unroll
    for (int kt = 0; kt < 4; ++kt) {
        s16x8 ah = *reinterpret_cast<const s16x8*>(Ah + abase + kt * 32);
        s16x8 al = *reinterpret_cast<const s16x8*>(Al + abase + kt * 32);
        const u16t* bb = Wcp + (kt * 10) * 1024 + ln * 8;
        #pragma unroll
        for (int nt = 0; nt < 10; ++nt) {
            s16x8 bh = *reinterpret_cast<const s16x8*>(bb + nt * 1024);
            s16x8 bl = *reinterpret_cast<const s16x8*>(bb + nt * 1024 + 512);
            acc[nt] = MFMA16(al, bh, acc[nt]);
            acc[nt] = MFMA16(ah, bl, acc[nt]);
            acc[nt] = MFMA16(ah, bh, acc[nt]);
        }
    }

    const int mrow = row0 + wave * 16 + quad * 4;
    #pragma unroll
    for (int nt = 0; nt < 8; ++nt) {
        int n = nt * 16 + col;
        float db = dtb[n];
        #pragma unroll
        for (int r = 0; r < 4; ++r) {
            float v = acc[nt][r] + db;
            v = v > 20.f ? v : log1pf(__expf(v));
            dt[(mrow + r) * DI + n] = v;
        }
    }
    #pragma unroll
    for (int r = 0; r < 4; ++r) {
        Bs[(mrow + r) * DS + col] = acc[8][r];
        Cs[(mrow + r) * DS + col] = acc[9][r];
    }
}

// ---------------------------------------------------------------------------
// K5a: scan pass A — per (b, chunk, channel): P = prod(dA), hp with h_in=0.
// ---------------------------------------------------------------------------
__global__ __launch_bounds__(128) void k5a(
    const float* __restrict__ dt, const float* __restrict__ u,
    const float* __restrict__ Bsb, const float* __restrict__ alog,
    float* __restrict__ P, float* __restrict__ HP)
{
    const int bk = blockIdx.x;
    const int b = bk / NC, k = bk - b * NC;
    const int c = threadIdx.x;
    float As[DS];
    #pragma unroll
    for (int s = 0; s < DS; ++s) As[s] = -__expf(alog[c * DS + s]);
    float Pp[DS], hp[DS];
    #pragma unroll
    for (int s = 0; s < DS; ++s) { Pp[s] = 1.f; hp[s] = 0.f; }

    const int l0 = k * CL;
    for (int i = 0; i < CL; ++i) {
        const int row = b * L_ + l0 + i;
        float dtv = dt[row * DI + c];
        float uv = u[row * DI + c];
        float dtu = dtv * uv;
        const float4* Bq = reinterpret_cast<const float4*>(Bsb + row * DS);
        float Bv[DS];
        #pragma unroll
        for (int q = 0; q < 4; ++q)
            *reinterpret_cast<float4*>(&Bv[q * 4]) = Bq[q];
        #pragma unroll
        for (int s = 0; s < DS; ++s) {
            float dA = __expf(dtv * As[s]);
            hp[s] = dA * hp[s] + dtu * Bv[s];
            Pp[s] *= dA;
        }
    }
    float* Pd = P + bk * 2048 + c * DS;
    float* Hd = HP + bk * 2048 + c * DS;
    #pragma unroll
    for (int q = 0; q < 4; ++q) {
        reinterpret_cast<float4*>(Pd)[q] = *reinterpret_cast<float4*>(&Pp[q * 4]);
        reinterpret_cast<float4*>(Hd)[q] = *reinterpret_cast<float4*>(&hp[q * 4]);
    }
}

// ---------------------------------------------------------------------------
// K5b: serial scan over NC chunk carries; carry-in written in-place over P.
// ---------------------------------------------------------------------------
__global__ __launch_bounds__(256) void k5b(
    float* __restrict__ P, const float* __restrict__ HP)
{
    const int t = blockIdx.x * 256 + threadIdx.x;
    const int b = t >> 11, cs = t & 2047;
    float carry = 0.f;
    for (int k = 0; k < NC; ++k) {
        const int idx = (b * NC + k) * 2048 + cs;
        float p = P[idx];
        float hp = HP[idx];
        P[idx] = carry;
        carry = hp + p * carry;
    }
}

// ---------------------------------------------------------------------------
// K5c: replay with h_in (from P), y = (h·C + u*D) * silu(z), in-place over u.
// ---------------------------------------------------------------------------
__global__ __launch_bounds__(128) void k5c(
    const float* __restrict__ dt, float* __restrict__ u,
    const float* __restrict__ Bsb, const float* __restrict__ Csb,
    const float* __restrict__ sz, const float* __restrict__ alog,
    const float* __restrict__ Db, const float* __restrict__ HI)
{
    const int bk = blockIdx.x;
    const int b = bk / NC, k = bk - b * NC;
    const int c = threadIdx.x;
    float As[DS];
    #pragma unroll
    for (int s = 0; s < DS; ++s) As[s] = -__expf(alog[c * DS + s]);
    const float Dc = Db[c];
    float h[DS];
    const float* Hs = HI + bk * 2048 + c * DS;
    #pragma unroll
    for (int q = 0; q < 4; ++q)
        *reinterpret_cast<float4*>(&h[q * 4]) = reinterpret_cast<const float4*>(Hs)[q];

    const int l0 = k * CL;
    for (int i = 0; i < CL; ++i) {
        const int row = b * L_ + l0 + i;
        float dtv = dt[row * DI + c];
        float uv = u[row * DI + c];
        float szv = sz[row * DI + c];
        float dtu = dtv * uv;
        const float4* Bq = reinterpret_cast<const float4*>(Bsb + row * DS);
        const float4* Cq = reinterpret_cast<const float4*>(Csb + row * DS);
        float Bv[DS], Cv[DS];
        #pragma unroll
        for (int q = 0; q < 4; ++q) {
            *reinterpret_cast<float4*>(&Bv[q * 4]) = Bq[q];
            *reinterpret_cast<float4*>(&Cv[q * 4]) = Cq[q];
        }
        float ya[4] = {0.f, 0.f, 0.f, 0.f};
        #pragma unroll
        for (int s = 0; s < DS; ++s) {
            float dA = __expf(dtv * As[s]);
            h[s] = dA * h[s] + dtu * Bv[s];
            ya[s & 3] += h[s] * Cv[s];
        }
        float yv = (ya[0] + ya[1]) + (ya[2] + ya[3]);
        u[row * DI + c] = (yv + uv * Dc) * szv;
    }
}

// ---------------------------------------------------------------------------
// G6: out_proj as split-bf16 MFMA GEMM + residual (+2*seq) + LDS-transposed
// NCHW store. 64 rows/block, N=64, K=128.
// ---------------------------------------------------------------------------
__global__ __launch_bounds__(256) void g6_outproj(
    const float* __restrict__ yc, const u16t* __restrict__ W6p,
    const float* __restrict__ seq, float* __restrict__ out)
{
    __shared__ u16t smem[2 * 64 * 136];   // Ah | Al ; Ah region reused as yT[64][68] f32
    u16t* Ah = smem;
    u16t* Al = smem + 64 * 136;
    const int t = threadIdx.x;
    const int row0 = blockIdx.x * 64;

    for (int idx = t; idx < 2048; idx += 256) {
        int r = idx >> 5, kq = (idx & 31) * 4;
        float4 v = *reinterpret_cast<const float4*>(yc + (row0 + r) * DI + kq);
        u16t h, l;
        split2(v.x, h, l); Ah[r * 136 + kq + 0] = h; Al[r * 136 + kq + 0] = l;
        split2(v.y, h, l); Ah[r * 136 + kq + 1] = h; Al[r * 136 + kq + 1] = l;
        split2(v.z, h, l); Ah[r * 136 + kq + 2] = h; Al[r * 136 + kq + 2] = l;
        split2(v.w, h, l); Ah[r * 136 + kq + 3] = h; Al[r * 136 + kq + 3] = l;
    }
    __syncthreads();

    const int wave = t >> 6, ln = t & 63, quad = ln >> 4, col = ln & 15;
    f32x4 acc[4];
    #pragma unroll
    for (int nt = 0; nt < 4; ++nt) acc[nt] = (f32x4){0.f, 0.f, 0.f, 0.f};

    const int abase = (wave * 16 + col) * 136 + quad * 8;
    #pragma unroll
    for (int kt = 0; kt < 4; ++kt) {
        s16x8 ah = *reinterpret_cast<const s16x8*>(Ah + abase + kt * 32);
        s16x8 al = *reinterpret_cast<const s16x8*>(Al + abase + kt * 32);
        const u16t* bb = W6p + (kt * 4) * 1024 + ln * 8;
        #pragma unroll
        for (int nt = 0; nt < 4; ++nt) {
            s16x8 bh = *reinterpret_cast<const s16x8*>(bb + nt * 1024);
            s16x8 bl = *reinterpret_cast<const s16x8*>(bb + nt * 1024 + 512);
            acc[nt] = MFMA16(al, bh, acc[nt]);
            acc[nt] = MFMA16(ah, bl, acc[nt]);
            acc[nt] = MFMA16(ah, bh, acc[nt]);
        }
    }
    __syncthreads();                      // done reading Ah/Al

    float* yT = reinterpret_cast<float*>(smem);   // [64][68]
    const int ml = wave * 16 + quad * 4;
    #pragma unroll
    for (int nt = 0; nt < 4; ++nt) {
        int n = nt * 16 + col;
        #pragma unroll
        for (int r = 0; r < 4; ++r) {
            int row = row0 + ml + r;
            yT[n * 68 + ml + r] = acc[nt][r] + 2.f * seq[row * 64 + n];
        }
    }
    __syncthreads();

    const int n = t >> 2;
    const int lq = (t & 3) * 16;
    const int b = row0 / L_;
    const int l0 = row0 % L_;
    float* op = out + (b * 64 + n) * L_ + l0 + lq;
    #pragma unroll
    for (int q = 0; q < 4; ++q) {
        float4 v = *reinterpret_cast<float4*>(&yT[n * 68 + lq + q * 4]);
        *reinterpret_cast<float4*>(op + q * 4) = v;
    }
}

extern "C" void kernel_launch(void* const* d_in, const int* in_sizes, int n_in,
                              void* d_out, int out_size, void* d_ws, size_t ws_size,
                              hipStream_t stream)
{
    const float* x    = (const float*)d_in[0];
    const float* cw   = (const float*)d_in[1];
    const float* cb   = (const float*)d_in[2];
    const float* g    = (const float*)d_in[3];
    const float* be   = (const float*)d_in[4];
    const float* ipw  = (const float*)d_in[5];
    const float* c1w  = (const float*)d_in[6];
    const float* c1b  = (const float*)d_in[7];
    const float* xpw  = (const float*)d_in[8];
    const float* dtw  = (const float*)d_in[9];
    const float* dtb  = (const float*)d_in[10];
    const float* alog = (const float*)d_in[11];
    const float* Db   = (const float*)d_in[12];
    const float* opw  = (const float*)d_in[13];

    float* ws  = (float*)d_ws;
    float* seq = ws;                      // 2,359,296
    float* nrm = seq + 2359296;           // 2,359,296 ; reused: Bs, Cs
    float* xm  = nrm + 2359296;           // 4,718,592 ; reused: P, HP
    float* sz  = xm + 4718592;            // 4,718,592
    float* u   = sz + 4718592;            // 4,718,592 ; k5c writes y in-place
    float* dt  = u + 4718592;             // 4,718,592
    u16t*  W2p = (u16t*)(dt + 4718592);   // 32,768 u16
    u16t*  Wcp = W2p + 32768;             // 40,960 u16
    u16t*  W6p = Wcp + 40960;             // 16,384 u16
    u16t*  Bp  = W6p + 16384;             // 32,768 u16
    // aliases (lifetimes disjoint with hosts)
    float* Bs  = nrm;                     // 589,824  (after g2)
    float* Cs  = nrm + 589824;            // 589,824
    float* P   = xm;                      // 2,097,152 (after k3; HI in-place)
    float* HP  = xm + 2097152;            // 2,097,152

    k0_prep   <<<480, 256, 0, stream>>>(ipw, xpw, dtw, opw, cw, W2p, Wcp, W6p, Bp);
    k1_conv_ln<<<576, 256, 0, stream>>>(x, Bp, cb, g, be, seq, nrm);
    g2_inproj <<<576, 256, 0, stream>>>(nrm, W2p, xm, sz);
    k3_dwconv <<<4608, 256, 0, stream>>>(xm, c1w, c1b, u);
    g4_xproj  <<<576, 256, 0, stream>>>(u, Wcp, dtb, dt, Bs, Cs);
    k5a       <<<B_ * NC, 128, 0, stream>>>(dt, u, Bs, alog, P, HP);
    k5b       <<<32, 256, 0, stream>>>(P, HP);
    k5c       <<<B_ * NC, 128, 0, stream>>>(dt, u, Bs, Cs, sz, alog, Db, P);
    g6_outproj<<<576, 256, 0, stream>>>(u, W6p, seq, (float*)d_out);
}